// Round 1
// baseline (5854.012 us; speedup 1.0000x reference)
//
#include <hip/hip_runtime.h>
#include <math.h>

#define TT 512
#define DD 1024
#define BB 32
#define G3D (3*DD)

typedef _Float16 f16;
typedef _Float16 f16x4 __attribute__((ext_vector_type(4)));
typedef _Float16 f16x8 __attribute__((ext_vector_type(8)));
typedef float f32x4 __attribute__((ext_vector_type(4)));

// ---------------------------------------------------------------- kernel A
// Convert weights fp32->fp16, zero h exchange buffers + barrier counter.
__global__ void k_convert(const float* __restrict__ Wih, const float* __restrict__ Whh,
                          f16* __restrict__ Wih16, f16* __restrict__ Whh16,
                          f16* __restrict__ h16, unsigned int* __restrict__ bar) {
    int idx = blockIdx.x * 256 + threadIdx.x;
    int n = G3D * DD;                       // 3,145,728
    if (idx < n) {
        Wih16[idx] = (f16)Wih[idx];
        Whh16[idx] = (f16)Whh[idx];
    }
    if (idx < 2 * BB * DD) h16[idx] = (f16)0.f;
    if (idx == 0) *bar = 0u;
}

// ---------------------------------------------------------------- kernel B
// GI[16384][3072] = h_enc[16384][1024] * Wih^T  + b_ih   (fp16 out)
// 128x128 tile, BK=32, 4 waves each 64x64, mfma_f32_16x16x32_f16.
#define BM 128
#define BN 128
#define BK 32
#define LDA 40   // halves per LDS row (pad 32 -> 40; 80B stride, 16B aligned)

__global__ __launch_bounds__(256) void k_pregemm(
    const float* __restrict__ X,      // [16384][1024] fp32
    const f16*   __restrict__ W16,    // [3072][1024] fp16
    const float* __restrict__ bih,    // [3072]
    f16* __restrict__ GI)             // [16384][3072] fp16
{
    __shared__ f16 As[BM * LDA];
    __shared__ f16 Bs[BN * LDA];
    const int tid  = threadIdx.x;
    const int lane = tid & 63;
    const int wave = tid >> 6;
    const int wr = wave >> 1, wc = wave & 1;
    const int m0 = blockIdx.y * BM;
    const int n0 = blockIdx.x * BN;
    const int mfrag = lane & 15;
    const int qfrag = lane >> 4;

    f32x4 acc[4][4] = {};

    for (int kt = 0; kt < DD; kt += BK) {
        __syncthreads();
        // stage A (fp32 -> fp16): 128 rows x 32 k
        {
            int row = tid >> 3;           // 0..31
            int c   = tid & 7;            // float4 chunk
            #pragma unroll
            for (int p = 0; p < 4; ++p) {
                int r = row + p * 32;
                float4 v = *(const float4*)(X + (size_t)(m0 + r) * DD + kt + c * 4);
                f16x4 hv = { (f16)v.x, (f16)v.y, (f16)v.z, (f16)v.w };
                *(f16x4*)(As + r * LDA + c * 4) = hv;
            }
        }
        // stage B (fp16 copy): 128 rows x 32 k
        {
            int row = tid >> 2;           // 0..63
            int c   = tid & 3;            // 8-half chunk
            #pragma unroll
            for (int p = 0; p < 2; ++p) {
                int r = row + p * 64;
                f16x8 v = *(const f16x8*)(W16 + (size_t)(n0 + r) * DD + kt + c * 8);
                *(f16x8*)(Bs + r * LDA + c * 8) = v;
            }
        }
        __syncthreads();
        f16x8 af[4], bf[4];
        #pragma unroll
        for (int i = 0; i < 4; ++i)
            af[i] = *(const f16x8*)(As + (wr * 64 + i * 16 + mfrag) * LDA + qfrag * 8);
        #pragma unroll
        for (int j = 0; j < 4; ++j)
            bf[j] = *(const f16x8*)(Bs + (wc * 64 + j * 16 + mfrag) * LDA + qfrag * 8);
        #pragma unroll
        for (int i = 0; i < 4; ++i)
            #pragma unroll
            for (int j = 0; j < 4; ++j)
                acc[i][j] = __builtin_amdgcn_mfma_f32_16x16x32_f16(af[i], bf[j], acc[i][j], 0, 0, 0);
    }
    // epilogue: add b_ih, store fp16. C/D: col=lane&15, row=(lane>>4)*4+reg
    #pragma unroll
    for (int j = 0; j < 4; ++j) {
        int col = n0 + wc * 64 + j * 16 + mfrag;
        float bias = bih[col];
        #pragma unroll
        for (int i = 0; i < 4; ++i) {
            int rowb = m0 + wr * 64 + i * 16 + qfrag * 4;
            #pragma unroll
            for (int r = 0; r < 4; ++r)
                GI[(size_t)(rowb + r) * G3D + col] = (f16)(acc[i][j][r] + bias);
        }
    }
}

// ---------------------------------------------------------------- kernel C
// Persistent recurrent kernel: 32 blocks x 256 threads (4 waves).
// Block bid owns h columns [bid*32, bid*32+32). W_hh slice lives in VGPRs.
__global__ __launch_bounds__(256, 1) void k_gru(
    const f16* __restrict__ Whh16,   // [3072][1024]
    const f16* __restrict__ GI,      // [16384][3072]
    const float* __restrict__ bhh,   // [3072]
    float* __restrict__ out,         // [32][512][1024] fp32
    f16* __restrict__ h16,           // [2][32][1024]
    unsigned int* __restrict__ bar)
{
    // stride 36 dwords => bank = (4*row + col) % 32 => <=2-way aliasing (free)
    __shared__ float red[4][3][32][36];
    __shared__ float h32[32][33];
    __shared__ float bh_s[3][32];

    const int tid  = threadIdx.x;
    const int lane = tid & 63;
    const int kq   = tid >> 6;        // wave id = K quarter
    const int j0   = blockIdx.x * 32;
    const int mfrag = lane & 15;
    const int qk    = lane >> 4;      // 0..3

    for (int i = tid; i < 32 * 33; i += 256) ((float*)h32)[i] = 0.f;
    if (tid < 96) bh_s[tid >> 5][tid & 31] = bhh[(tid >> 5) * DD + j0 + (tid & 31)];

    // Pre-load W_hh B-fragments into registers: wf[gate][coltile][k-iter]
    f16x8 wf[3][2][8];
    #pragma unroll
    for (int g = 0; g < 3; ++g)
        #pragma unroll
        for (int ct = 0; ct < 2; ++ct)
            #pragma unroll
            for (int it = 0; it < 8; ++it) {
                int row = g * DD + j0 + ct * 16 + mfrag;
                int k   = kq * 256 + it * 32 + qk * 8;
                wf[g][ct][it] = *(const f16x8*)(Whh16 + (size_t)row * DD + k);
            }
    __syncthreads();

    const int cj  = tid & 31;
    const int cbg = tid >> 5;         // 0..7

    for (int t = 0; t < TT; ++t) {
        const int par = t & 1;

        // prefetch gi for this step (latency hides under MFMA phase)
        f16 giv[4][3];
        #pragma unroll
        for (int u = 0; u < 4; ++u) {
            int b = u * 8 + cbg;
            const f16* gp = GI + (size_t)(b * TT + t) * G3D + j0 + cj;
            #pragma unroll
            for (int g = 0; g < 3; ++g) giv[u][g] = gp[g * (size_t)DD];
        }

        // A-fragments of h (fp16 broadcast buffer)
        f16x8 af[8][2];
        #pragma unroll
        for (int it = 0; it < 8; ++it)
            #pragma unroll
            for (int rt = 0; rt < 2; ++rt)
                af[it][rt] = *(const f16x8*)(h16 + (size_t)par * BB * DD +
                                             (rt * 16 + mfrag) * DD + kq * 256 + it * 32 + qk * 8);

        f32x4 acc[3][2][2] = {};
        #pragma unroll
        for (int it = 0; it < 8; ++it)
            #pragma unroll
            for (int g = 0; g < 3; ++g)
                #pragma unroll
                for (int ct = 0; ct < 2; ++ct)
                    #pragma unroll
                    for (int rt = 0; rt < 2; ++rt)
                        acc[g][ct][rt] = __builtin_amdgcn_mfma_f32_16x16x32_f16(
                            af[it][rt], wf[g][ct][it], acc[g][ct][rt], 0, 0, 0);

        // dump K-partials to LDS. C/D: col=lane&15, row=(lane>>4)*4+reg
        #pragma unroll
        for (int g = 0; g < 3; ++g)
            #pragma unroll
            for (int ct = 0; ct < 2; ++ct)
                #pragma unroll
                for (int rt = 0; rt < 2; ++rt)
                    #pragma unroll
                    for (int r = 0; r < 4; ++r)
                        red[kq][g][rt * 16 + qk * 4 + r][ct * 16 + mfrag] = acc[g][ct][rt][r];
        __syncthreads();

        // combine: thread handles column cj for 4 batch rows
        #pragma unroll
        for (int u = 0; u < 4; ++u) {
            int b = u * 8 + cbg;
            float ghr = red[0][0][b][cj] + red[1][0][b][cj] + red[2][0][b][cj] + red[3][0][b][cj];
            float ghz = red[0][1][b][cj] + red[1][1][b][cj] + red[2][1][b][cj] + red[3][1][b][cj];
            float ghn = red[0][2][b][cj] + red[1][2][b][cj] + red[2][2][b][cj] + red[3][2][b][cj];
            float pr = (float)giv[u][0] + ghr + bh_s[0][cj];
            float pz = (float)giv[u][1] + ghz + bh_s[1][cj];
            float r  = 1.f / (1.f + __expf(-pr));
            float z  = 1.f / (1.f + __expf(-pz));
            float pn = (float)giv[u][2] + r * (ghn + bh_s[2][cj]);
            float e  = __expf(-2.f * fabsf(pn));
            float tn = (1.f - e) / (1.f + e);
            tn = pn < 0.f ? -tn : tn;
            float hold = h32[b][cj];
            float hnew = tn + z * (hold - tn);      // (1-z)*n + z*h
            h32[b][cj] = hnew;
            out[(size_t)(b * TT + t) * DD + j0 + cj] = hnew;
            h16[(size_t)(par ^ 1) * BB * DD + b * DD + j0 + cj] = (f16)hnew;
        }

        __threadfence();          // release our h16/out stores device-wide
        __syncthreads();          // all threads fenced; also all red reads done
        if (tid == 0) {
            __hip_atomic_fetch_add(bar, 1u, __ATOMIC_RELEASE, __HIP_MEMORY_SCOPE_AGENT);
            unsigned int target = 32u * (unsigned)(t + 1);
            while (__hip_atomic_load(bar, __ATOMIC_ACQUIRE, __HIP_MEMORY_SCOPE_AGENT) < target)
                __builtin_amdgcn_s_sleep(1);
        }
        __syncthreads();
        __threadfence();          // acquire side: invalidate caches before next h read
    }
}

// ---------------------------------------------------------------- launch
extern "C" void kernel_launch(void* const* d_in, const int* in_sizes, int n_in,
                              void* d_out, int out_size, void* d_ws, size_t ws_size,
                              hipStream_t stream) {
    const float* h_enc = (const float*)d_in[0];
    const float* Wih   = (const float*)d_in[1];
    const float* Whh   = (const float*)d_in[2];
    const float* bih   = (const float*)d_in[3];
    const float* bhh   = (const float*)d_in[4];
    float* out = (float*)d_out;

    char* ws = (char*)d_ws;
    // ws layout (bytes): GI 100663296 | Wih16 6291456 | Whh16 6291456 | h16 131072 | bar 64
    f16* GI     = (f16*)(ws);
    f16* Wih16  = (f16*)(ws + 100663296);
    f16* Whh16  = (f16*)(ws + 106954752);
    f16* h16    = (f16*)(ws + 113246208);
    unsigned int* bar = (unsigned int*)(ws + 113377280);

    hipLaunchKernelGGL(k_convert, dim3(12288), dim3(256), 0, stream,
                       Wih, Whh, Wih16, Whh16, h16, bar);
    hipLaunchKernelGGL(k_pregemm, dim3(BN == 128 ? 24 : 24, 128), dim3(256), 0, stream,
                       h_enc, Wih16, bih, GI);
    hipLaunchKernelGGL(k_gru, dim3(32), dim3(256), 0, stream,
                       Whh16, GI, bhh, out, h16, bar);
}

// Round 2
// 3747.813 us; speedup vs baseline: 1.5620x; 1.5620x over previous
//
#include <hip/hip_runtime.h>
#include <math.h>

#define TT 512
#define DD 1024
#define BB 32
#define G3D (3*DD)

typedef _Float16 f16;
typedef _Float16 f16x2 __attribute__((ext_vector_type(2)));
typedef _Float16 f16x4 __attribute__((ext_vector_type(4)));
typedef _Float16 f16x8 __attribute__((ext_vector_type(8)));
typedef float f32x4 __attribute__((ext_vector_type(4)));
typedef unsigned long long u64;

// ---------------------------------------------------------------- kernel A
// Convert weights fp32->fp16, zero h exchange buffers + barrier counter.
__global__ void k_convert(const float* __restrict__ Wih, const float* __restrict__ Whh,
                          f16* __restrict__ Wih16, f16* __restrict__ Whh16,
                          f16* __restrict__ h16, unsigned int* __restrict__ bar) {
    int idx = blockIdx.x * 256 + threadIdx.x;
    int n = G3D * DD;                       // 3,145,728
    if (idx < n) {
        Wih16[idx] = (f16)Wih[idx];
        Whh16[idx] = (f16)Whh[idx];
    }
    if (idx < 2 * BB * DD) h16[idx] = (f16)0.f;
    if (idx == 0) *bar = 0u;
}

// ---------------------------------------------------------------- kernel B
// GI[16384][3072] = h_enc[16384][1024] * Wih^T  + b_ih   (fp16 out)
// 128x128 tile, BK=32, 4 waves each 64x64, mfma_f32_16x16x32_f16.
#define BM 128
#define BN 128
#define BK 32
#define LDA 40   // halves per LDS row (pad 32 -> 40; 80B stride, 16B aligned)

__global__ __launch_bounds__(256) void k_pregemm(
    const float* __restrict__ X,      // [16384][1024] fp32
    const f16*   __restrict__ W16,    // [3072][1024] fp16
    const float* __restrict__ bih,    // [3072]
    f16* __restrict__ GI)             // [16384][3072] fp16
{
    __shared__ f16 As[BM * LDA];
    __shared__ f16 Bs[BN * LDA];
    const int tid  = threadIdx.x;
    const int lane = tid & 63;
    const int wave = tid >> 6;
    const int wr = wave >> 1, wc = wave & 1;
    const int m0 = blockIdx.y * BM;
    const int n0 = blockIdx.x * BN;
    const int mfrag = lane & 15;
    const int qfrag = lane >> 4;

    f32x4 acc[4][4] = {};

    for (int kt = 0; kt < DD; kt += BK) {
        __syncthreads();
        // stage A (fp32 -> fp16): 128 rows x 32 k
        {
            int row = tid >> 3;           // 0..31
            int c   = tid & 7;            // float4 chunk
            #pragma unroll
            for (int p = 0; p < 4; ++p) {
                int r = row + p * 32;
                float4 v = *(const float4*)(X + (size_t)(m0 + r) * DD + kt + c * 4);
                f16x4 hv = { (f16)v.x, (f16)v.y, (f16)v.z, (f16)v.w };
                *(f16x4*)(As + r * LDA + c * 4) = hv;
            }
        }
        // stage B (fp16 copy): 128 rows x 32 k
        {
            int row = tid >> 2;           // 0..63
            int c   = tid & 3;            // 8-half chunk
            #pragma unroll
            for (int p = 0; p < 2; ++p) {
                int r = row + p * 64;
                f16x8 v = *(const f16x8*)(W16 + (size_t)(n0 + r) * DD + kt + c * 8);
                *(f16x8*)(Bs + r * LDA + c * 8) = v;
            }
        }
        __syncthreads();
        f16x8 af[4], bf[4];
        #pragma unroll
        for (int i = 0; i < 4; ++i)
            af[i] = *(const f16x8*)(As + (wr * 64 + i * 16 + mfrag) * LDA + qfrag * 8);
        #pragma unroll
        for (int j = 0; j < 4; ++j)
            bf[j] = *(const f16x8*)(Bs + (wc * 64 + j * 16 + mfrag) * LDA + qfrag * 8);
        #pragma unroll
        for (int i = 0; i < 4; ++i)
            #pragma unroll
            for (int j = 0; j < 4; ++j)
                acc[i][j] = __builtin_amdgcn_mfma_f32_16x16x32_f16(af[i], bf[j], acc[i][j], 0, 0, 0);
    }
    // epilogue: add b_ih, store fp16. C/D: col=lane&15, row=(lane>>4)*4+reg
    #pragma unroll
    for (int j = 0; j < 4; ++j) {
        int col = n0 + wc * 64 + j * 16 + mfrag;
        float bias = bih[col];
        #pragma unroll
        for (int i = 0; i < 4; ++i) {
            int rowb = m0 + wr * 64 + i * 16 + qfrag * 4;
            #pragma unroll
            for (int r = 0; r < 4; ++r)
                GI[(size_t)(rowb + r) * G3D + col] = (f16)(acc[i][j][r] + bias);
        }
    }
}

// ---------------------------------------------------------------- kernel C
// Persistent recurrent kernel: 32 blocks x 256 threads (4 waves).
// Block bid owns h columns [bid*32, bid*32+32). W_hh slice lives in VGPRs.
// All cross-block data (h16, bar) via relaxed agent-scope atomics (sc0 sc1,
// LLC-coherent, NO full-L2 wbl2/inv). No __threadfence anywhere.
__global__ __launch_bounds__(256, 1) void k_gru(
    const f16* __restrict__ Whh16,   // [3072][1024]
    const f16* __restrict__ GI,      // [16384][3072]
    const float* __restrict__ bhh,   // [3072]
    float* __restrict__ out,         // [32][512][1024] fp32
    f16* __restrict__ h16,           // [2][32][1024] exchange buffer
    unsigned int* __restrict__ bar)
{
    // stride 36 dwords => <=2-way bank aliasing on MFMA dump (free)
    __shared__ float red[4][3][32][36];
    __shared__ float h32[32][34];
    __shared__ float bh_s[3][32];

    const int tid  = threadIdx.x;
    const int lane = tid & 63;
    const int kq   = tid >> 6;        // wave id = K quarter
    const int j0   = blockIdx.x * 32;
    const int mfrag = lane & 15;
    const int qk    = lane >> 4;      // 0..3

    for (int i = tid; i < 32 * 34; i += 256) ((float*)h32)[i] = 0.f;
    if (tid < 96) bh_s[tid >> 5][tid & 31] = bhh[(tid >> 5) * DD + j0 + (tid & 31)];

    // Pre-load W_hh B-fragments into registers: wf[gate][coltile][k-iter]
    f16x8 wf[3][2][8];
    #pragma unroll
    for (int g = 0; g < 3; ++g)
        #pragma unroll
        for (int ct = 0; ct < 2; ++ct)
            #pragma unroll
            for (int it = 0; it < 8; ++it) {
                int row = g * DD + j0 + ct * 16 + mfrag;
                int k   = kq * 256 + it * 32 + qk * 8;
                wf[g][ct][it] = *(const f16x8*)(Whh16 + (size_t)row * DD + k);
            }
    __syncthreads();

    const int c2 = (tid & 15) * 2;    // combine: even col pair
    const int bg = tid >> 4;          // 0..15 -> rows {bg, bg+16}

    for (int t = 0; t < TT; ++t) {
        const int par = t & 1;

        // prefetch gi for this step (cached loads; latency hides under MFMA)
        f16x2 giv[2][3];
        #pragma unroll
        for (int u = 0; u < 2; ++u) {
            int b = bg + u * 16;
            const f16* gp = GI + (size_t)(b * TT + t) * G3D + j0 + c2;
            #pragma unroll
            for (int g = 0; g < 3; ++g) giv[u][g] = *(const f16x2*)(gp + g * (size_t)DD);
        }

        // A-fragments of h: relaxed agent atomic 8B loads (LLC-coherent)
        const u64* hb = (const u64*)(h16 + (size_t)par * BB * DD);
        f16x8 af[8][2];
        #pragma unroll
        for (int it = 0; it < 8; ++it)
            #pragma unroll
            for (int rt = 0; rt < 2; ++rt) {
                int base = ((rt * 16 + mfrag) * DD + kq * 256 + it * 32 + qk * 8) >> 2;
                union { u64 u[2]; f16x8 v; } tmp;
                tmp.u[0] = __hip_atomic_load(hb + base,     __ATOMIC_RELAXED, __HIP_MEMORY_SCOPE_AGENT);
                tmp.u[1] = __hip_atomic_load(hb + base + 1, __ATOMIC_RELAXED, __HIP_MEMORY_SCOPE_AGENT);
                af[it][rt] = tmp.v;
            }

        f32x4 acc[3][2][2] = {};
        #pragma unroll
        for (int it = 0; it < 8; ++it)
            #pragma unroll
            for (int g = 0; g < 3; ++g)
                #pragma unroll
                for (int ct = 0; ct < 2; ++ct)
                    #pragma unroll
                    for (int rt = 0; rt < 2; ++rt)
                        acc[g][ct][rt] = __builtin_amdgcn_mfma_f32_16x16x32_f16(
                            af[it][rt], wf[g][ct][it], acc[g][ct][rt], 0, 0, 0);

        // dump K-partials to LDS. C/D: col=lane&15, row=(lane>>4)*4+reg
        #pragma unroll
        for (int g = 0; g < 3; ++g)
            #pragma unroll
            for (int ct = 0; ct < 2; ++ct)
                #pragma unroll
                for (int rt = 0; rt < 2; ++rt)
                    #pragma unroll
                    for (int r = 0; r < 4; ++r)
                        red[kq][g][rt * 16 + qk * 4 + r][ct * 16 + mfrag] = acc[g][ct][rt][r];
        __syncthreads();

        // combine: thread handles cols {c2,c2+1} for rows {bg, bg+16}
        #pragma unroll
        for (int u = 0; u < 2; ++u) {
            int b = bg + u * 16;
            float2 gr = make_float2(0.f, 0.f), gz = gr, gn = gr;
            #pragma unroll
            for (int q = 0; q < 4; ++q) {
                float2 vr = *(const float2*)&red[q][0][b][c2];
                float2 vz = *(const float2*)&red[q][1][b][c2];
                float2 vn = *(const float2*)&red[q][2][b][c2];
                gr.x += vr.x; gr.y += vr.y;
                gz.x += vz.x; gz.y += vz.y;
                gn.x += vn.x; gn.y += vn.y;
            }
            float hnew[2];
            #pragma unroll
            for (int cc = 0; cc < 2; ++cc) {
                float ghr = cc ? gr.y : gr.x;
                float ghz = cc ? gz.y : gz.x;
                float ghn = cc ? gn.y : gn.x;
                float pr = (float)giv[u][0][cc] + ghr + bh_s[0][c2 + cc];
                float pz = (float)giv[u][1][cc] + ghz + bh_s[1][c2 + cc];
                float r  = 1.f / (1.f + __expf(-pr));
                float z  = 1.f / (1.f + __expf(-pz));
                float pn = (float)giv[u][2][cc] + r * (ghn + bh_s[2][c2 + cc]);
                float e  = __expf(-2.f * fabsf(pn));
                float tn = (1.f - e) / (1.f + e);
                tn = pn < 0.f ? -tn : tn;
                float hold = h32[b][c2 + cc];
                float hn2 = tn + z * (hold - tn);   // (1-z)*n + z*h
                h32[b][c2 + cc] = hn2;
                hnew[cc] = hn2;
            }
            // out: normal cached store (host-visible at kernel end)
            *(float2*)(out + (size_t)(b * TT + t) * DD + j0 + c2) = make_float2(hnew[0], hnew[1]);
            // h16 publish: packed u32 relaxed agent atomic store (LLC-coherent)
            union { unsigned int u; f16x2 h; } pk;
            pk.h[0] = (f16)hnew[0]; pk.h[1] = (f16)hnew[1];
            unsigned int* hp = (unsigned int*)h16;
            __hip_atomic_store(hp + (((par ^ 1) * BB * DD + b * DD + j0 + c2) >> 1), pk.u,
                               __ATOMIC_RELAXED, __HIP_MEMORY_SCOPE_AGENT);
        }

        // drain all vmem (incl. h16 atomic stores), then counter barrier.
        __builtin_amdgcn_s_waitcnt(0x0F70);   // vmcnt(0)
        __syncthreads();                      // all waves drained
        if (tid == 0) {
            __hip_atomic_fetch_add(bar, 1u, __ATOMIC_RELAXED, __HIP_MEMORY_SCOPE_AGENT);
            unsigned int target = 32u * (unsigned)(t + 1);
            while (__hip_atomic_load(bar, __ATOMIC_RELAXED, __HIP_MEMORY_SCOPE_AGENT) < target)
                __builtin_amdgcn_s_sleep(2);
        }
        __syncthreads();
    }
}

// ---------------------------------------------------------------- launch
extern "C" void kernel_launch(void* const* d_in, const int* in_sizes, int n_in,
                              void* d_out, int out_size, void* d_ws, size_t ws_size,
                              hipStream_t stream) {
    const float* h_enc = (const float*)d_in[0];
    const float* Wih   = (const float*)d_in[1];
    const float* Whh   = (const float*)d_in[2];
    const float* bih   = (const float*)d_in[3];
    const float* bhh   = (const float*)d_in[4];
    float* out = (float*)d_out;

    char* ws = (char*)d_ws;
    // ws layout (bytes): GI 100663296 | Wih16 6291456 | Whh16 6291456 | h16 131072 | bar 64
    f16* GI     = (f16*)(ws);
    f16* Wih16  = (f16*)(ws + 100663296);
    f16* Whh16  = (f16*)(ws + 106954752);
    f16* h16    = (f16*)(ws + 113246208);
    unsigned int* bar = (unsigned int*)(ws + 113377280);

    hipLaunchKernelGGL(k_convert, dim3(12288), dim3(256), 0, stream,
                       Wih, Whh, Wih16, Whh16, h16, bar);
    hipLaunchKernelGGL(k_pregemm, dim3(24, 128), dim3(256), 0, stream,
                       h_enc, Wih16, bih, GI);
    hipLaunchKernelGGL(k_gru, dim3(32), dim3(256), 0, stream,
                       Whh16, GI, bhh, out, h16, bar);
}